// Round 1
// 307.951 us; speedup vs baseline: 1.0679x; 1.0679x over previous
//
#include <hip/hip_runtime.h>
#include <hip/hip_bf16.h>
#include <math.h>

#define NUM_B 4
#define SEQ 512
#define HID 1024
#define NH 50          // 2 ent + 24 head + 24 tail
#define NCOL 6400      // NH * 128
#define M_TOK 2048     // NUM_B * SEQ

typedef short bf16x8_t __attribute__((ext_vector_type(8)));
typedef float f32x4_t __attribute__((ext_vector_type(4)));

__device__ __forceinline__ unsigned short f2bf(float f) {
    union { float f; unsigned int u; } v; v.f = f;
    unsigned int u = v.u;
    u += 0x7fffu + ((u >> 16) & 1u);
    return (unsigned short)(u >> 16);
}

__device__ __forceinline__ void gload_lds16(const void* g, void* l) {
    __builtin_amdgcn_global_load_lds(
        (__attribute__((address_space(1))) unsigned int*)(unsigned long long)g,
        (__attribute__((address_space(3))) unsigned int*)(unsigned long long)(uintptr_t)l,
        16, 0, 0);
}

// ---------------- prep: x fp32->bf16, packed cos/sin table, bias concat -----
// csT[p*16 + t2] = (cos(p*div[t2]), sin(p*div[t2])), t2 = (dim&31)>>1
__global__ void k_prep(const float* __restrict__ x, unsigned short* __restrict__ xb,
                       float2* __restrict__ csT,
                       const float* __restrict__ be, const float* __restrict__ bh,
                       const float* __restrict__ bt, float* __restrict__ ball) {
    int bid = blockIdx.x, tid = threadIdx.x;
    if (bid < 2048) {                       // x convert: 2048*256 float4
        int i = bid * 256 + tid;
        float4 v = ((const float4*)x)[i];
        ushort4 o;
        o.x = f2bf(v.x); o.y = f2bf(v.y); o.z = f2bf(v.z); o.w = f2bf(v.w);
        ((ushort4*)xb)[i] = o;
    } else if (bid < 2112) {                // cos/sin table: 1024*16 entries
        int idx = (bid - 2048) * 256 + tid;
        int p = idx >> 4, t2 = idx & 15;
        float ang = (float)p * expf(-logf(10000.f) * (float)(2 * t2) / 32.f);
        csT[idx] = make_float2(cosf(ang), sinf(ang));
    } else {                                // bias concat: 6400
        int i = (bid - 2112) * 256 + tid;
        if (i < 6400) {
            float v;
            if (i < 256) v = be[i];
            else if (i < 3328) v = bh[i - 256];
            else v = bt[i - 3328];
            ball[i] = v;
        }
    }
}

// ---------------- all W (K x Nw) -> Wt (6400 x 1024) bf16 transpose ---------
__global__ void k_cvt_w(const float* __restrict__ We, const float* __restrict__ Wh,
                        const float* __restrict__ Wl, unsigned short* __restrict__ Wo) {
    __shared__ float t[32][33];
    int n = blockIdx.x * 32 + threadIdx.x;     // segments are 32-aligned
    const float* W; int Nw, nc;
    if (n < 256)       { W = We; Nw = 256;  nc = n; }
    else if (n < 3328) { W = Wh; Nw = 3072; nc = n - 256; }
    else               { W = Wl; Nw = 3072; nc = n - 3328; }
    int k = blockIdx.y * 32 + threadIdx.y;
    t[threadIdx.y][threadIdx.x] = W[(size_t)k * Nw + nc];
    __syncthreads();
    int on = blockIdx.x * 32 + threadIdx.y;
    int ok = blockIdx.y * 32 + threadIdx.x;
    Wo[(size_t)on * HID + ok] = f2bf(t[threadIdx.x][threadIdx.y]);
}

// ---------------- fused per-(b,h): GEMM1+bias+RoPE -> LDS Q/K -> QK^T -> out
// Phase 1: Q|K[512][128] = xb[b] (512x1024) @ Wt[h*128..+128] (bf16 MFMA,
//          swapped operands: acc rows = n (q*4+r), cols = m (l15))
// Phase 2: S[512][512] = Q @ K^T / 8, tril (h<2), mask, fp32 out.
// LDS: [0,64K) As (phase1 A-tile, aliased by Qs in phase2)
//      [64K,80K) Bs (phase1 B-tile)
//      [80K,144K) Ks (phase2 K panel)
#define FUSED_LDS_BYTES (144 * 1024)

__global__ __launch_bounds__(512, 2) void k_fused(const unsigned short* __restrict__ xb,
                                                  const unsigned short* __restrict__ Wt,
                                                  const float* __restrict__ bias,
                                                  const int* __restrict__ xp,
                                                  const int* __restrict__ yp,
                                                  const float2* __restrict__ csT,
                                                  const int* __restrict__ mask,
                                                  float* __restrict__ out) {
    extern __shared__ unsigned short smem[];
    unsigned short* As = smem;              // [512][64]  64 KB
    unsigned short* Bs = smem + 512 * 64;   // [128][64]  16 KB
    unsigned short* Qs = smem;              // [512][64]  aliases As (after barrier)
    unsigned short* Ks = smem + 640 * 64;   // [512][64]  64 KB @ +80 KB

    int tid = threadIdx.x;
    int wave = tid >> 6, lane = tid & 63;
    int l15 = lane & 15, q = lane >> 4;
    int bh = blockIdx.x;
    int b = bh / NH, h = bh - b * NH;

    const unsigned short* Ab = xb + (size_t)b * SEQ * HID;
    const unsigned short* Bb = Wt + (size_t)h * 128 * HID;

    f32x4_t acc[8][4];
#pragma unroll
    for (int i = 0; i < 8; i++)
#pragma unroll
        for (int j = 0; j < 4; j++) acc[i][j] = (f32x4_t){0.f, 0.f, 0.f, 0.f};

    int wmg = (wave >> 1) * 128;   // this wave's 128-token m-group
    int wqk = wave & 1;            // 0 => Q columns, 1 => K columns

    // ---- phase 1: Q|K = A @ B^T over K=1024, BK=64 ----
    for (int k0 = 0; k0 < HID; k0 += 64) {
        __syncthreads();
#pragma unroll
        for (int it = 0; it < 8; ++it) {           // As: 512x64 bf16 = 4096 chunks
            int c = it * 512 + tid;
            int r = c >> 3, cl = c & 7;
            int cg = cl ^ (r & 7);                  // XOR swizzle (source side)
            gload_lds16(Ab + (size_t)r * HID + k0 + cg * 8, As + c * 8);
        }
#pragma unroll
        for (int it = 0; it < 2; ++it) {           // Bs: 128x64 bf16 = 1024 chunks
            int c = it * 512 + tid;
            int r = c >> 3, cl = c & 7;
            int cg = cl ^ (r & 7);
            gload_lds16(Bb + (size_t)r * HID + k0 + cg * 8, Bs + c * 8);
        }
        __syncthreads();
#pragma unroll
        for (int ks = 0; ks < 2; ++ks) {
            bf16x8_t af[8], bfr[4];
#pragma unroll
            for (int i = 0; i < 8; i++) {
                int r = wmg + i * 16 + l15;
                int cl = (ks * 4 + q) ^ (r & 7);
                af[i] = *(const bf16x8_t*)&As[r * 64 + cl * 8];
            }
#pragma unroll
            for (int j = 0; j < 4; j++) {
                int r = wqk * 64 + j * 16 + l15;
                int cl = (ks * 4 + q) ^ (r & 7);
                bfr[j] = *(const bf16x8_t*)&Bs[r * 64 + cl * 8];
            }
#pragma unroll
            for (int i = 0; i < 8; i++)
#pragma unroll
                for (int j = 0; j < 4; j++)
                    acc[i][j] = __builtin_amdgcn_mfma_f32_16x16x32_bf16(bfr[j], af[i], acc[i][j], 0, 0, 0);
        }
    }

    __syncthreads();   // all LDS reads of As/Bs done before Qs (alias) writes

    // ---- phase 1 epilogue: +bias, RoPE, bf16 -> swizzled LDS Q/K panels ----
    float4 bj[4];
#pragma unroll
    for (int j = 0; j < 4; j++)
        bj[j] = *(const float4*)&bias[h * 128 + wqk * 64 + j * 16 + q * 4];
    unsigned short* dst = wqk ? Ks : Qs;
#pragma unroll
    for (int i = 0; i < 8; i++) {
        int m = wmg + i * 16 + l15;                 // local token row
        int mg = b * SEQ + m;
        int posx = xp[mg] * 16, posy = yp[mg] * 16;
#pragma unroll
        for (int j = 0; j < 4; j++) {
            float v0 = acc[i][j][0] + bj[j].x;
            float v1 = acc[i][j][1] + bj[j].y;
            float v2 = acc[i][j][2] + bj[j].z;
            float v3 = acc[i][j][3] + bj[j].w;
            // head-dim dd = j*16 + q*4 + r  (dd<32 -> x_pos, else y_pos)
            int pos = (j < 2) ? posx : posy;
            int t2 = (j & 1) * 8 + q * 2;
            float2 cs0 = csT[pos + t2];
            float2 cs1 = csT[pos + t2 + 1];
            float r0 = v0 * cs0.x - v1 * cs0.y;
            float r1 = v1 * cs0.x + v0 * cs0.y;
            float r2 = v2 * cs1.x - v3 * cs1.y;
            float r3 = v3 * cs1.x + v2 * cs1.y;
            ushort4 o;
            o.x = f2bf(r0); o.y = f2bf(r1); o.z = f2bf(r2); o.w = f2bf(r3);
            // write 4 bf16 at (row m, dd=j*16+q*4) with the same chunk swizzle
            int cl0 = j * 2 + (q >> 1);             // 16B-chunk index dd>>3
            int swz = cl0 ^ (m & 7);
            *(ushort4*)&dst[m * 64 + swz * 8 + (q & 1) * 4] = o;
        }
    }
    __syncthreads();

    // ---- phase 2: S = Q @ K^T (contraction over d=64, 2 MFMA K-steps) ----
    bf16x8_t qf[4][2];
#pragma unroll
    for (int i = 0; i < 4; i++) {
        int r = wave * 64 + i * 16 + l15;           // this wave's m rows
#pragma unroll
        for (int ks = 0; ks < 2; ks++) {
            int cl = (ks * 4 + q) ^ (r & 7);
            qf[i][ks] = *(const bf16x8_t*)&Qs[r * 64 + cl * 8];
        }
    }

    const int* mrow = mask + b * SEQ;
    bool enth = (h < 2);
    size_t obase = (size_t)bh * SEQ * SEQ;
    int mloc[4]; bool mz[4];
#pragma unroll
    for (int i = 0; i < 4; i++) {
        mloc[i] = wave * 64 + i * 16 + l15;
        mz[i] = (mrow[mloc[i]] == 0);
    }

    for (int nc = 0; nc < 8; ++nc) {               // n-chunks of 64 cols
        bf16x8_t kf[4][2];
#pragma unroll
        for (int j = 0; j < 4; j++) {
            int r = nc * 64 + j * 16 + l15;
#pragma unroll
            for (int ks = 0; ks < 2; ks++) {
                int cl = (ks * 4 + q) ^ (r & 7);
                kf[j][ks] = *(const bf16x8_t*)&Ks[r * 64 + cl * 8];
            }
        }
        f32x4_t a2[4][4];
#pragma unroll
        for (int i = 0; i < 4; i++)
#pragma unroll
            for (int j = 0; j < 4; j++) a2[i][j] = (f32x4_t){0.f, 0.f, 0.f, 0.f};
#pragma unroll
        for (int ks = 0; ks < 2; ks++)
#pragma unroll
            for (int i = 0; i < 4; i++)
#pragma unroll
                for (int j = 0; j < 4; j++)
                    a2[i][j] = __builtin_amdgcn_mfma_f32_16x16x32_bf16(kf[j][ks], qf[i][ks], a2[i][j], 0, 0, 0);

        int4 mn[4];
#pragma unroll
        for (int j = 0; j < 4; j++)
            mn[j] = *(const int4*)&mrow[nc * 64 + j * 16 + q * 4];
#pragma unroll
        for (int i = 0; i < 4; i++) {
            int m = mloc[i];
#pragma unroll
            for (int j = 0; j < 4; j++) {
                int nb = nc * 64 + j * 16 + q * 4;
                float4 v;
                v.x = a2[i][j][0] * 0.125f;
                v.y = a2[i][j][1] * 0.125f;
                v.z = a2[i][j][2] * 0.125f;
                v.w = a2[i][j][3] * 0.125f;
                if (enth) {
                    if (m > nb)     v.x -= 1.25e11f;
                    if (m > nb + 1) v.y -= 1.25e11f;
                    if (m > nb + 2) v.z -= 1.25e11f;
                    if (m > nb + 3) v.w -= 1.25e11f;
                }
                if (mz[i] || mn[j].x == 0) v.x = -INFINITY;
                if (mz[i] || mn[j].y == 0) v.y = -INFINITY;
                if (mz[i] || mn[j].z == 0) v.z = -INFINITY;
                if (mz[i] || mn[j].w == 0) v.w = -INFINITY;
                *(float4*)&out[obase + (size_t)m * SEQ + nb] = v;
            }
        }
    }
}

extern "C" void kernel_launch(void* const* d_in, const int* in_sizes, int n_in,
                              void* d_out, int out_size, void* d_ws, size_t ws_size,
                              hipStream_t stream) {
    const float* x      = (const float*)d_in[0];
    const int*   mask   = (const int*)d_in[1];
    const int*   xp     = (const int*)d_in[2];
    const int*   yp     = (const int*)d_in[3];
    const float* W_ent  = (const float*)d_in[4];
    const float* b_ent  = (const float*)d_in[5];
    const float* W_head = (const float*)d_in[6];
    const float* b_head = (const float*)d_in[7];
    const float* W_tail = (const float*)d_in[8];
    const float* b_tail = (const float*)d_in[9];
    float* out = (float*)d_out;

    char* ws = (char*)d_ws;
    size_t off = 0;
    auto alloc = [&](size_t bytes) {
        void* p = ws + off;
        off += (bytes + 255) & ~(size_t)255;
        return p;
    };
    float2* csT = (float2*)alloc(16384 * 8);
    unsigned short* xb  = (unsigned short*)alloc((size_t)M_TOK * HID * 2);
    unsigned short* Wt  = (unsigned short*)alloc((size_t)NCOL * HID * 2);
    float* ball = (float*)alloc(NCOL * 4);

    static bool attr_done = false;
    if (!attr_done) {
        (void)hipFuncSetAttribute((const void*)k_fused,
                                  hipFuncAttributeMaxDynamicSharedMemorySize,
                                  FUSED_LDS_BYTES);
        attr_done = true;
    }

    k_prep<<<2137, 256, 0, stream>>>(x, xb, csT, b_ent, b_head, b_tail, ball);
    k_cvt_w<<<dim3(200, 32), dim3(32, 32), 0, stream>>>(W_ent, W_head, W_tail, Wt);
    k_fused<<<NUM_B * NH, 512, FUSED_LDS_BYTES, stream>>>(xb, Wt, ball, xp, yp, csT, mask, out);
}